// Round 15
// baseline (364.022 us; speedup 1.0000x reference)
//
#include <hip/hip_runtime.h>
#include <hip/hip_bf16.h>

#define N_NODES 50000
#define N_EDGES 800000
#define IN_DIM 128
#define F_SIZE 64
#define N_GRAPHS 512
#define OUT_DIM 10
#define EDGE_CHUNK 2048
#define NCHUNKS ((N_EDGES + EDGE_CHUNK - 1) / EDGE_CHUNK)   // 391
#define NODES_PER_XCD ((N_NODES + 7) / 8)                    // 6250
#define SLICE_NODES (NODES_PER_XCD / 2)                      // 3125 (L2-resident bucket slice)
#define GEMM_BLOCKS 782        // ceil(50000/64)
#define CAP 48                 // per-node CSR bucket capacity (max degree ~45 @ Poisson(16))

// ---------------- utility ----------------
__global__ void k_zero_int(int* __restrict__ p, int n) {
    int i = blockIdx.x * blockDim.x + threadIdx.x;
    if (i < n) p[i] = 0;
}

// ---------------- XCD-partitioned, L2-sliced direct scatter ----------------
// 2 slices per XCD: per-slice bucket footprint 3125*576B = 1.8MB < 4MB L2, so each
// bucket line stays resident for its whole fill and writes back once.
__global__ __launch_bounds__(256) void k_scatter_direct(const int* __restrict__ ind0,
                                                        const int* __restrict__ ind1,
                                                        const float* __restrict__ vals,
                                                        int* __restrict__ cnt0, int* __restrict__ cnt1,
                                                        int2* __restrict__ c0pack, int* __restrict__ c1src) {
    int xcd = blockIdx.x & 7;
    int sc = blockIdx.x >> 3;               // [0, 2*NCHUNKS)
    int slice = sc / NCHUNKS;               // 0 first, then 1 (temporal separation)
    int chunk = sc % NCHUNKS;
    int lo = xcd * NODES_PER_XCD + slice * SLICE_NODES;
    int hi = lo + SLICE_NODES;
    int base = chunk * EDGE_CHUNK;
    int end = base + EDGE_CHUNK; if (end > N_EDGES) end = N_EDGES;
    for (int e = base + threadIdx.x; e < end; e += 256) {
        int r = ind0[e];
        int c = ind1[e];
        if (r >= lo && r < hi) {
            int p0 = atomicAdd(&cnt0[r], 1);
            c0pack[r * CAP + p0] = make_int2(c, __float_as_int(vals[e]));
        }
        if (c >= lo && c < hi) {
            int p1 = atomicAdd(&cnt1[c], 1);
            c1src[c * CAP + p1] = r;
        }
    }
}

// ---------------- layer-1 triple GEMM: G{0,1,2} = X @ W1[seg]  (X staged once) ----------------
#define AT_STRIDE 68
__global__ __launch_bounds__(256) void k_gemm1x3(const float* __restrict__ X,
                                                 const float* __restrict__ W1,
                                                 float* __restrict__ G0,
                                                 float* __restrict__ G1,
                                                 float* __restrict__ G2) {
    __shared__ float At[64 * AT_STRIDE];
    __shared__ float Wl[64 * 64];
    const int t = threadIdx.x;
    const int l = t & 63, w = t >> 6;
    const int r0 = blockIdx.x * 64;
    const int rbase = w * 16 + (l >> 4) * 4;
    const int cbase = (l & 15) * 4;
    float acc[3][4][4] = {};

    #pragma unroll
    for (int ch = 0; ch < 2; ++ch) {
        const int koff = ch * 64;
        #pragma unroll
        for (int i = 0; i < 4; ++i) {
            int f   = i * 256 + t;
            int row = f >> 4;
            int kq  = f & 15;
            int gr  = r0 + row; if (gr > N_NODES - 1) gr = N_NODES - 1;
            float4 v = *(const float4*)(X + (size_t)gr * IN_DIM + koff + kq * 4);
            At[(kq * 4 + 0) * AT_STRIDE + row] = v.x;
            At[(kq * 4 + 1) * AT_STRIDE + row] = v.y;
            At[(kq * 4 + 2) * AT_STRIDE + row] = v.z;
            At[(kq * 4 + 3) * AT_STRIDE + row] = v.w;
        }
        #pragma unroll
        for (int sg = 0; sg < 3; ++sg) {
            const float4* Wg = (const float4*)(W1 + ((size_t)sg * 128 + koff) * 64);
            float4 wtmp[4];
            #pragma unroll
            for (int i = 0; i < 4; ++i) wtmp[i] = Wg[i * 256 + t];
            __syncthreads();
            #pragma unroll
            for (int i = 0; i < 4; ++i) *(float4*)&Wl[(i * 256 + t) * 4] = wtmp[i];
            __syncthreads();
            #pragma unroll 8
            for (int k = 0; k < 64; ++k) {
                float4 a4 = *(const float4*)&At[k * AT_STRIDE + rbase];
                float4 w4 = *(const float4*)&Wl[k * 64 + cbase];
                acc[sg][0][0] += a4.x * w4.x; acc[sg][0][1] += a4.x * w4.y; acc[sg][0][2] += a4.x * w4.z; acc[sg][0][3] += a4.x * w4.w;
                acc[sg][1][0] += a4.y * w4.x; acc[sg][1][1] += a4.y * w4.y; acc[sg][1][2] += a4.y * w4.z; acc[sg][1][3] += a4.y * w4.w;
                acc[sg][2][0] += a4.z * w4.x; acc[sg][2][1] += a4.z * w4.y; acc[sg][2][2] += a4.z * w4.z; acc[sg][2][3] += a4.z * w4.w;
                acc[sg][3][0] += a4.w * w4.x; acc[sg][3][1] += a4.w * w4.y; acc[sg][3][2] += a4.w * w4.z; acc[sg][3][3] += a4.w * w4.w;
            }
        }
        __syncthreads();
    }
    float* Gs[3] = {G0, G1, G2};
    #pragma unroll
    for (int sg = 0; sg < 3; ++sg) {
        #pragma unroll
        for (int r = 0; r < 4; ++r) {
            int gr = r0 + rbase + r;
            if (gr < N_NODES) {
                float4 o = {acc[sg][r][0], acc[sg][r][1], acc[sg][r][2], acc[sg][r][3]};
                *(float4*)&Gs[sg][(size_t)gr * 64 + cbase] = o;
            }
        }
    }
}

// ---------------- float4-gather SpMM: wave = 4 nodes, 16 lanes/row ----------------
// MODE 0: dst = A + 2*acc            MODE 1: dst = dis*(acc + A - Bb), dis inline from cnt1
template<int MODE>
__global__ __launch_bounds__(256) void k_spmm64v(const int* __restrict__ cnt0, const int2* __restrict__ pack,
                          const float4* __restrict__ src4, const float4* __restrict__ A4,
                          const float4* __restrict__ B4, const int* __restrict__ cnt1,
                          float4* __restrict__ dst4) {
    int t = blockIdx.x * blockDim.x + threadIdx.x;
    int wid = t >> 6, lane = t & 63;
    int grp = lane >> 4, sub = lane & 15;
    int node = wid * 4 + grp;
    if (node >= N_NODES) return;
    int s = node * CAP;
    int e = s + cnt0[node];
    float4 acc = {0.f, 0.f, 0.f, 0.f};
    int j = s;
    for (; j + 3 < e; j += 4) {
        int2 p0 = pack[j], p1 = pack[j + 1], p2 = pack[j + 2], p3 = pack[j + 3];
        float4 r0 = src4[(size_t)p0.x * 16 + sub];
        float4 r1 = src4[(size_t)p1.x * 16 + sub];
        float4 r2 = src4[(size_t)p2.x * 16 + sub];
        float4 r3 = src4[(size_t)p3.x * 16 + sub];
        float v0 = __int_as_float(p0.y), v1 = __int_as_float(p1.y);
        float v2 = __int_as_float(p2.y), v3 = __int_as_float(p3.y);
        acc.x += v0 * r0.x + v1 * r1.x + v2 * r2.x + v3 * r3.x;
        acc.y += v0 * r0.y + v1 * r1.y + v2 * r2.y + v3 * r3.y;
        acc.z += v0 * r0.z + v1 * r1.z + v2 * r2.z + v3 * r3.z;
        acc.w += v0 * r0.w + v1 * r1.w + v2 * r2.w + v3 * r3.w;
    }
    for (; j < e; ++j) {
        int2 p = pack[j];
        float4 r = src4[(size_t)p.x * 16 + sub];
        float v = __int_as_float(p.y);
        acc.x += v * r.x; acc.y += v * r.y; acc.z += v * r.z; acc.w += v * r.w;
    }
    size_t idx = (size_t)node * 16 + sub;
    float4 a = A4[idx];
    float4 o;
    if (MODE == 0) {
        o.x = a.x + 2.f * acc.x; o.y = a.y + 2.f * acc.y;
        o.z = a.z + 2.f * acc.z; o.w = a.w + 2.f * acc.w;
    } else {
        float4 bb = B4[idx];
        float d = rsqrtf(1.0f + (float)cnt1[node]);
        o.x = d * (acc.x + a.x - bb.x); o.y = d * (acc.y + a.y - bb.y);
        o.z = d * (acc.z + a.z - bb.z); o.w = d * (acc.w + a.w - bb.w);
    }
    dst4[idx] = o;
}

// ---------------- float4-gather conv ----------------
// FINAL=0: x = relu(dis*(acc + self) + b)
// FINAL=1: xm = (x1 + x2 + relu(...))/3   (layer-3 output feeds only the pool)
template<int FINAL>
__global__ void k_conv_gatherv(const int* __restrict__ cnt1, const int* __restrict__ csrc,
                               const float4* __restrict__ hp4,
                               const float* __restrict__ b,
                               const float4* __restrict__ x1v, const float4* __restrict__ x2v,
                               float4* __restrict__ x4) {
    int t = blockIdx.x * blockDim.x + threadIdx.x;
    int wid = t >> 6, lane = t & 63;
    int grp = lane >> 4, sub = lane & 15;
    int node = wid * 4 + grp;
    if (node >= N_NODES) return;
    int deg = cnt1[node];
    int s = node * CAP;
    int e = s + deg;
    float4 acc = {0.f, 0.f, 0.f, 0.f};
    int j = s;
    for (; j + 3 < e; j += 4) {
        int s0 = csrc[j], s1 = csrc[j + 1], s2 = csrc[j + 2], s3 = csrc[j + 3];
        float4 r0 = hp4[(size_t)s0 * 16 + sub];
        float4 r1 = hp4[(size_t)s1 * 16 + sub];
        float4 r2 = hp4[(size_t)s2 * 16 + sub];
        float4 r3 = hp4[(size_t)s3 * 16 + sub];
        acc.x += (r0.x + r1.x) + (r2.x + r3.x);
        acc.y += (r0.y + r1.y) + (r2.y + r3.y);
        acc.z += (r0.z + r1.z) + (r2.z + r3.z);
        acc.w += (r0.w + r1.w) + (r2.w + r3.w);
    }
    for (; j < e; ++j) {
        float4 r = hp4[(size_t)csrc[j] * 16 + sub];
        acc.x += r.x; acc.y += r.y; acc.z += r.z; acc.w += r.w;
    }
    size_t idx = (size_t)node * 16 + sub;
    float4 sl = hp4[idx];                 // self loop
    float d = rsqrtf(1.0f + (float)deg);
    float4 bv = ((const float4*)b)[sub];
    float4 o;
    o.x = fmaxf(d * (acc.x + sl.x) + bv.x, 0.f);
    o.y = fmaxf(d * (acc.y + sl.y) + bv.y, 0.f);
    o.z = fmaxf(d * (acc.z + sl.z) + bv.z, 0.f);
    o.w = fmaxf(d * (acc.w + sl.w) + bv.w, 0.f);
    if (FINAL) {
        float4 a1 = x1v[idx], a2 = x2v[idx];
        const float third = 1.f / 3.f;
        o.x = (a1.x + a2.x + o.x) * third;
        o.y = (a1.y + a2.y + o.y) * third;
        o.z = (a1.z + a2.z + o.z) * third;
        o.w = (a1.w + a2.w + o.w) * third;
    }
    x4[idx] = o;
}

// ---------------- LDS-tiled fp32 GEMM: C = dis ⊙ (s0 @ W), dis inline from cnt1 ----------------
__global__ __launch_bounds__(256) void k_gemm64(const float* __restrict__ s0,
                                                const float* __restrict__ W,
                                                const int* __restrict__ cnt1,
                                                float* __restrict__ C) {
    __shared__ float At[64 * AT_STRIDE];
    __shared__ float Wl[64 * 64];
    const int t = threadIdx.x;
    const int l = t & 63, w = t >> 6;
    const int r0 = blockIdx.x * 64;
    const int rbase = w * 16 + (l >> 4) * 4;
    const int cbase = (l & 15) * 4;
    float acc[4][4] = {};

    {
        const float4* Wg = (const float4*)W;
        #pragma unroll
        for (int i = 0; i < 4; ++i) *(float4*)&Wl[(i * 256 + t) * 4] = Wg[i * 256 + t];
    }
    #pragma unroll
    for (int i = 0; i < 4; ++i) {
        int f   = i * 256 + t;
        int row = f >> 4;
        int kq  = f & 15;
        int gr  = r0 + row; if (gr > N_NODES - 1) gr = N_NODES - 1;
        float4 v = *(const float4*)(s0 + (size_t)gr * 64 + kq * 4);
        At[(kq * 4 + 0) * AT_STRIDE + row] = v.x;
        At[(kq * 4 + 1) * AT_STRIDE + row] = v.y;
        At[(kq * 4 + 2) * AT_STRIDE + row] = v.z;
        At[(kq * 4 + 3) * AT_STRIDE + row] = v.w;
    }
    __syncthreads();
    #pragma unroll 8
    for (int k = 0; k < 64; ++k) {
        float4 a4 = *(const float4*)&At[k * AT_STRIDE + rbase];
        float4 w4 = *(const float4*)&Wl[k * 64 + cbase];
        acc[0][0] += a4.x * w4.x; acc[0][1] += a4.x * w4.y; acc[0][2] += a4.x * w4.z; acc[0][3] += a4.x * w4.w;
        acc[1][0] += a4.y * w4.x; acc[1][1] += a4.y * w4.y; acc[1][2] += a4.y * w4.z; acc[1][3] += a4.y * w4.w;
        acc[2][0] += a4.z * w4.x; acc[2][1] += a4.z * w4.y; acc[2][2] += a4.z * w4.z; acc[2][3] += a4.z * w4.w;
        acc[3][0] += a4.w * w4.x; acc[3][1] += a4.w * w4.y; acc[3][2] += a4.w * w4.z; acc[3][3] += a4.w * w4.w;
    }
    #pragma unroll
    for (int r = 0; r < 4; ++r) {
        int gr = r0 + rbase + r;
        if (gr < N_NODES) {
            float d = rsqrtf(1.0f + (float)cnt1[gr]);
            float4 o = {d * acc[r][0], d * acc[r][1], d * acc[r][2], d * acc[r][3]};
            *(float4*)&C[(size_t)gr * 64 + cbase] = o;
        }
    }
}

// ---------------- pool (batch sorted -> contiguous ranges) + head, 4 waves ----------------
__global__ __launch_bounds__(256) void k_pool_out(const float* __restrict__ xm,
                           const int* __restrict__ batch,
                           const float* __restrict__ Wout, const float* __restrict__ bout,
                           float* __restrict__ out) {
    __shared__ float red[4][64];
    __shared__ float sh[64];
    __shared__ float logits[OUT_DIM];
    int g = blockIdx.x;
    int t = threadIdx.x, f = t & 63, w = t >> 6;
    int lo = 0, hi = N_NODES;
    while (lo < hi) { int m = (lo + hi) >> 1; if (batch[m] < g) lo = m + 1; else hi = m; }
    int start = lo;
    hi = N_NODES;
    while (lo < hi) { int m = (lo + hi) >> 1; if (batch[m] < g + 1) lo = m + 1; else hi = m; }
    int end = lo;
    float a = 0.f;
    for (int i = start + w; i < end; i += 4)
        a += xm[(size_t)i * 64 + f];
    red[w][f] = a;
    __syncthreads();
    if (w == 0) {
        float cnt = (float)((end - start) > 0 ? (end - start) : 1);
        sh[f] = (red[0][f] + red[1][f] + red[2][f] + red[3][f]) / cnt;
    }
    __syncthreads();
    if (t < OUT_DIM) {
        float l = bout[t];
        for (int k = 0; k < 64; ++k) l += sh[k] * Wout[k * OUT_DIM + t];
        logits[t] = l;
    }
    __syncthreads();
    if (t < OUT_DIM) {
        float m = logits[0];
        for (int k = 1; k < OUT_DIM; ++k) m = fmaxf(m, logits[k]);
        float ssum = 0.f;
        for (int k = 0; k < OUT_DIM; ++k) ssum += expf(logits[k] - m);
        out[(size_t)g * OUT_DIM + t] = expf(logits[t] - m) / ssum;
    }
}

extern "C" void kernel_launch(void* const* d_in, const int* in_sizes, int n_in,
                              void* d_out, int out_size, void* d_ws, size_t ws_size,
                              hipStream_t stream) {
    const float* X     = (const float*)d_in[0];
    const int*   Lind  = (const int*)d_in[1];
    const int*   ind0  = Lind;
    const int*   ind1  = Lind + N_EDGES;
    const float* vals  = (const float*)d_in[2];
    const int*   batch = (const int*)d_in[3];
    const float* W1    = (const float*)d_in[4];
    const float* b1    = (const float*)d_in[5];
    const float* W2    = (const float*)d_in[6];
    const float* b2    = (const float*)d_in[7];
    const float* W3    = (const float*)d_in[8];
    const float* b3    = (const float*)d_in[9];
    const float* Wout  = (const float*)d_in[10];
    const float* bout  = (const float*)d_in[11];
    float* out = (float*)d_out;

    // workspace layout (4B words; feature buffers at %4==0 word offsets -> 16B aligned)
    int* cnt0    = (int*)d_ws;                 // 50000 (degree of ind0 after scatter)
    int* cnt1    = cnt0 + 50000;               // 50000 (degree of ind1 = GCN deg)
    int2* c0pack = (int2*)(cnt1 + 50000);      // 50000*CAP int2
    int*  c1src  = (int*)(c0pack + 50000 * CAP);  // 50000*CAP int
    float* G0    = (float*)(c1src + 50000 * CAP); // 3,200,000
    float* G1    = G0 + 3200000;
    float* G2    = G1 + 3200000;
    float* R     = G2 + 3200000;
    float* h     = R  + 3200000;
    // buffer reuse after producers die:
    float* x1    = G0;   // dead after spmm1
    float* x2    = G1;   // dead after spmm0
    float* xm    = R;    // dead after spmm1

    const int B = 256;
    const int gatherGrid = 12500 * 64 / B;                // 3125 blocks (4 nodes/wave)
    const int tileGrid = GEMM_BLOCKS;                     // 782
    const int partGrid = NCHUNKS * 8 * 2;                 // 6256 (2 slices/XCD)

    // direct CSR build (no hist / no scan), L2-sliced
    k_zero_int<<<(100000 + B - 1) / B, B, 0, stream>>>(cnt0, 100000);  // cnt0+cnt1 contiguous
    k_scatter_direct<<<partGrid, B, 0, stream>>>(ind0, ind1, vals, cnt0, cnt1, c0pack, c1src);

    // layer-1 GEMMs: G0/G1/G2 = X @ W1 segments
    k_gemm1x3<<<tileGrid, B, 0, stream>>>(X, W1, G0, G1, G2);

    // Chebyshev via linearity (64-dim spmms, float4 gathers):
    // R = G1 + 2*(L@G2);  h1' = dis*(L@R + G0 - G2)
    k_spmm64v<0><<<gatherGrid, B, 0, stream>>>(cnt0, c0pack, (const float4*)G2,
                                               (const float4*)G1, nullptr, cnt1, (float4*)R);
    k_spmm64v<1><<<gatherGrid, B, 0, stream>>>(cnt0, c0pack, (const float4*)R,
                                               (const float4*)G0, (const float4*)G2, cnt1, (float4*)h);

    // layer 1 conv (writes x1 into G0's space — G0 dead after spmm1)
    k_conv_gatherv<0><<<gatherGrid, B, 0, stream>>>(cnt1, c1src, (const float4*)h, b1,
                                                    nullptr, nullptr, (float4*)x1);

    // layer 2: h2' = dis*(x1@W2), conv (x2 into G1's space)
    k_gemm64<<<tileGrid, B, 0, stream>>>(x1, W2, cnt1, h);
    k_conv_gatherv<0><<<gatherGrid, B, 0, stream>>>(cnt1, c1src, (const float4*)h, b2,
                                                    nullptr, nullptr, (float4*)x2);

    // layer 3: conv writes xm = (x1+x2+x3)/3 directly (into R's space)
    k_gemm64<<<tileGrid, B, 0, stream>>>(x2, W3, cnt1, h);
    k_conv_gatherv<1><<<gatherGrid, B, 0, stream>>>(cnt1, c1src, (const float4*)h, b3,
                                                    (const float4*)x1, (const float4*)x2, (float4*)xm);

    // pool + head
    k_pool_out<<<N_GRAPHS, B, 0, stream>>>(xm, batch, Wout, bout, out);
}

// Round 16
// 295.573 us; speedup vs baseline: 1.2316x; 1.2316x over previous
//
#include <hip/hip_runtime.h>
#include <hip/hip_bf16.h>

#define N_NODES 50000
#define N_EDGES 800000
#define IN_DIM 128
#define F_SIZE 64
#define N_GRAPHS 512
#define OUT_DIM 10
#define EDGE_CHUNK 2048
#define NCHUNKS ((N_EDGES + EDGE_CHUNK - 1) / EDGE_CHUNK)   // 391
#define NODES_PER_XCD ((N_NODES + 7) / 8)                    // 6250
#define GEMM_BLOCKS 782        // ceil(50000/64)
#define CAP 48                 // per-node CSR bucket capacity (max degree ~45 @ Poisson(16))

// ---------------- bf16 pack/unpack helpers (round-to-nearest-even) ----------------
__device__ __forceinline__ unsigned int pack_bf2(float a, float b) {
    unsigned int ua = __float_as_uint(a);
    unsigned int ub = __float_as_uint(b);
    ua += 0x7fffu + ((ua >> 16) & 1u);
    ub += 0x7fffu + ((ub >> 16) & 1u);
    return (ua >> 16) | (ub & 0xffff0000u);
}
__device__ __forceinline__ uint2 pack_f4(float4 o) {
    return make_uint2(pack_bf2(o.x, o.y), pack_bf2(o.z, o.w));
}
__device__ __forceinline__ float4 unpack_f4(uint2 u) {
    float4 f;
    f.x = __uint_as_float(u.x << 16);
    f.y = __uint_as_float(u.x & 0xffff0000u);
    f.z = __uint_as_float(u.y << 16);
    f.w = __uint_as_float(u.y & 0xffff0000u);
    return f;
}

// ---------------- utility ----------------
__global__ void k_zero_int(int* __restrict__ p, int n) {
    int i = blockIdx.x * blockDim.x + threadIdx.x;
    if (i < n) p[i] = 0;
}

// ---------------- XCD-partitioned direct scatter (R14 config: no slicing) ----------------
__global__ __launch_bounds__(256) void k_scatter_direct(const int* __restrict__ ind0,
                                                        const int* __restrict__ ind1,
                                                        const float* __restrict__ vals,
                                                        int* __restrict__ cnt0, int* __restrict__ cnt1,
                                                        int2* __restrict__ c0pack, int* __restrict__ c1src) {
    int xcd = blockIdx.x & 7;
    int chunk = blockIdx.x >> 3;
    int lo = xcd * NODES_PER_XCD, hi = lo + NODES_PER_XCD;
    int base = chunk * EDGE_CHUNK;
    int end = base + EDGE_CHUNK; if (end > N_EDGES) end = N_EDGES;
    for (int e = base + threadIdx.x; e < end; e += 256) {
        int r = ind0[e];
        int c = ind1[e];
        if (r >= lo && r < hi) {
            int p0 = atomicAdd(&cnt0[r], 1);
            c0pack[r * CAP + p0] = make_int2(c, __float_as_int(vals[e]));
        }
        if (c >= lo && c < hi) {
            int p1 = atomicAdd(&cnt1[c], 1);
            c1src[c * CAP + p1] = r;
        }
    }
}

// ---------------- layer-1 triple GEMM: G0,G1 fp32; G2 bf16 (it is gathered) ----------------
#define AT_STRIDE 68
__global__ __launch_bounds__(256) void k_gemm1x3(const float* __restrict__ X,
                                                 const float* __restrict__ W1,
                                                 float* __restrict__ G0,
                                                 float* __restrict__ G1,
                                                 uint2* __restrict__ G2bf) {
    __shared__ float At[64 * AT_STRIDE];
    __shared__ float Wl[64 * 64];
    const int t = threadIdx.x;
    const int l = t & 63, w = t >> 6;
    const int r0 = blockIdx.x * 64;
    const int rbase = w * 16 + (l >> 4) * 4;
    const int cbase = (l & 15) * 4;
    float acc[3][4][4] = {};

    #pragma unroll
    for (int ch = 0; ch < 2; ++ch) {
        const int koff = ch * 64;
        #pragma unroll
        for (int i = 0; i < 4; ++i) {
            int f   = i * 256 + t;
            int row = f >> 4;
            int kq  = f & 15;
            int gr  = r0 + row; if (gr > N_NODES - 1) gr = N_NODES - 1;
            float4 v = *(const float4*)(X + (size_t)gr * IN_DIM + koff + kq * 4);
            At[(kq * 4 + 0) * AT_STRIDE + row] = v.x;
            At[(kq * 4 + 1) * AT_STRIDE + row] = v.y;
            At[(kq * 4 + 2) * AT_STRIDE + row] = v.z;
            At[(kq * 4 + 3) * AT_STRIDE + row] = v.w;
        }
        #pragma unroll
        for (int sg = 0; sg < 3; ++sg) {
            const float4* Wg = (const float4*)(W1 + ((size_t)sg * 128 + koff) * 64);
            float4 wtmp[4];
            #pragma unroll
            for (int i = 0; i < 4; ++i) wtmp[i] = Wg[i * 256 + t];
            __syncthreads();
            #pragma unroll
            for (int i = 0; i < 4; ++i) *(float4*)&Wl[(i * 256 + t) * 4] = wtmp[i];
            __syncthreads();
            #pragma unroll 8
            for (int k = 0; k < 64; ++k) {
                float4 a4 = *(const float4*)&At[k * AT_STRIDE + rbase];
                float4 w4 = *(const float4*)&Wl[k * 64 + cbase];
                acc[sg][0][0] += a4.x * w4.x; acc[sg][0][1] += a4.x * w4.y; acc[sg][0][2] += a4.x * w4.z; acc[sg][0][3] += a4.x * w4.w;
                acc[sg][1][0] += a4.y * w4.x; acc[sg][1][1] += a4.y * w4.y; acc[sg][1][2] += a4.y * w4.z; acc[sg][1][3] += a4.y * w4.w;
                acc[sg][2][0] += a4.z * w4.x; acc[sg][2][1] += a4.z * w4.y; acc[sg][2][2] += a4.z * w4.z; acc[sg][2][3] += a4.z * w4.w;
                acc[sg][3][0] += a4.w * w4.x; acc[sg][3][1] += a4.w * w4.y; acc[sg][3][2] += a4.w * w4.z; acc[sg][3][3] += a4.w * w4.w;
            }
        }
        __syncthreads();
    }
    #pragma unroll
    for (int r = 0; r < 4; ++r) {
        int gr = r0 + rbase + r;
        if (gr < N_NODES) {
            float4 o0 = {acc[0][r][0], acc[0][r][1], acc[0][r][2], acc[0][r][3]};
            float4 o1 = {acc[1][r][0], acc[1][r][1], acc[1][r][2], acc[1][r][3]};
            float4 o2 = {acc[2][r][0], acc[2][r][1], acc[2][r][2], acc[2][r][3]};
            *(float4*)&G0[(size_t)gr * 64 + cbase] = o0;
            *(float4*)&G1[(size_t)gr * 64 + cbase] = o1;
            G2bf[(size_t)gr * 16 + (l & 15)] = pack_f4(o2);
        }
    }
}

// ---------------- bf16-gather SpMM: wave = 4 nodes, 16 lanes/row ----------------
// MODE 0: Rbf = A(G1,fp32) + 2*acc(src=G2bf)
// MODE 1: hbf = dis*(acc(src=Rbf) + A(G0,fp32) - B(G2bf))
template<int MODE>
__global__ __launch_bounds__(256) void k_spmm64v(const int* __restrict__ cnt0, const int2* __restrict__ pack,
                          const uint2* __restrict__ srcbf, const float4* __restrict__ A4,
                          const uint2* __restrict__ Bbf, const int* __restrict__ cnt1,
                          uint2* __restrict__ dstbf) {
    int t = blockIdx.x * blockDim.x + threadIdx.x;
    int wid = t >> 6, lane = t & 63;
    int grp = lane >> 4, sub = lane & 15;
    int node = wid * 4 + grp;
    if (node >= N_NODES) return;
    int s = node * CAP;
    int e = s + cnt0[node];
    float4 acc = {0.f, 0.f, 0.f, 0.f};
    int j = s;
    for (; j + 3 < e; j += 4) {
        int2 p0 = pack[j], p1 = pack[j + 1], p2 = pack[j + 2], p3 = pack[j + 3];
        float4 r0 = unpack_f4(srcbf[(size_t)p0.x * 16 + sub]);
        float4 r1 = unpack_f4(srcbf[(size_t)p1.x * 16 + sub]);
        float4 r2 = unpack_f4(srcbf[(size_t)p2.x * 16 + sub]);
        float4 r3 = unpack_f4(srcbf[(size_t)p3.x * 16 + sub]);
        float v0 = __int_as_float(p0.y), v1 = __int_as_float(p1.y);
        float v2 = __int_as_float(p2.y), v3 = __int_as_float(p3.y);
        acc.x += v0 * r0.x + v1 * r1.x + v2 * r2.x + v3 * r3.x;
        acc.y += v0 * r0.y + v1 * r1.y + v2 * r2.y + v3 * r3.y;
        acc.z += v0 * r0.z + v1 * r1.z + v2 * r2.z + v3 * r3.z;
        acc.w += v0 * r0.w + v1 * r1.w + v2 * r2.w + v3 * r3.w;
    }
    for (; j < e; ++j) {
        int2 p = pack[j];
        float4 r = unpack_f4(srcbf[(size_t)p.x * 16 + sub]);
        float v = __int_as_float(p.y);
        acc.x += v * r.x; acc.y += v * r.y; acc.z += v * r.z; acc.w += v * r.w;
    }
    size_t idx = (size_t)node * 16 + sub;
    float4 a = A4[idx];
    float4 o;
    if (MODE == 0) {
        o.x = a.x + 2.f * acc.x; o.y = a.y + 2.f * acc.y;
        o.z = a.z + 2.f * acc.z; o.w = a.w + 2.f * acc.w;
    } else {
        float4 bb = unpack_f4(Bbf[idx]);
        float d = rsqrtf(1.0f + (float)cnt1[node]);
        o.x = d * (acc.x + a.x - bb.x); o.y = d * (acc.y + a.y - bb.y);
        o.z = d * (acc.z + a.z - bb.z); o.w = d * (acc.w + a.w - bb.w);
    }
    dstbf[idx] = pack_f4(o);
}

// ---------------- bf16-gather conv ----------------
// FINAL=0: x = relu(dis*(acc + self) + b)          (x fp32)
// FINAL=1: xm = (x1 + x2 + relu(...))/3
template<int FINAL>
__global__ void k_conv_gatherv(const int* __restrict__ cnt1, const int* __restrict__ csrc,
                               const uint2* __restrict__ hbf,
                               const float* __restrict__ b,
                               const float4* __restrict__ x1v, const float4* __restrict__ x2v,
                               float4* __restrict__ x4) {
    int t = blockIdx.x * blockDim.x + threadIdx.x;
    int wid = t >> 6, lane = t & 63;
    int grp = lane >> 4, sub = lane & 15;
    int node = wid * 4 + grp;
    if (node >= N_NODES) return;
    int deg = cnt1[node];
    int s = node * CAP;
    int e = s + deg;
    float4 acc = {0.f, 0.f, 0.f, 0.f};
    int j = s;
    for (; j + 3 < e; j += 4) {
        int s0 = csrc[j], s1 = csrc[j + 1], s2 = csrc[j + 2], s3 = csrc[j + 3];
        float4 r0 = unpack_f4(hbf[(size_t)s0 * 16 + sub]);
        float4 r1 = unpack_f4(hbf[(size_t)s1 * 16 + sub]);
        float4 r2 = unpack_f4(hbf[(size_t)s2 * 16 + sub]);
        float4 r3 = unpack_f4(hbf[(size_t)s3 * 16 + sub]);
        acc.x += (r0.x + r1.x) + (r2.x + r3.x);
        acc.y += (r0.y + r1.y) + (r2.y + r3.y);
        acc.z += (r0.z + r1.z) + (r2.z + r3.z);
        acc.w += (r0.w + r1.w) + (r2.w + r3.w);
    }
    for (; j < e; ++j) {
        float4 r = unpack_f4(hbf[(size_t)csrc[j] * 16 + sub]);
        acc.x += r.x; acc.y += r.y; acc.z += r.z; acc.w += r.w;
    }
    size_t idx = (size_t)node * 16 + sub;
    float4 sl = unpack_f4(hbf[idx]);      // self loop
    float d = rsqrtf(1.0f + (float)deg);
    float4 bv = ((const float4*)b)[sub];
    float4 o;
    o.x = fmaxf(d * (acc.x + sl.x) + bv.x, 0.f);
    o.y = fmaxf(d * (acc.y + sl.y) + bv.y, 0.f);
    o.z = fmaxf(d * (acc.z + sl.z) + bv.z, 0.f);
    o.w = fmaxf(d * (acc.w + sl.w) + bv.w, 0.f);
    if (FINAL) {
        float4 a1 = x1v[idx], a2 = x2v[idx];
        const float third = 1.f / 3.f;
        o.x = (a1.x + a2.x + o.x) * third;
        o.y = (a1.y + a2.y + o.y) * third;
        o.z = (a1.z + a2.z + o.z) * third;
        o.w = (a1.w + a2.w + o.w) * third;
    }
    x4[idx] = o;
}

// ---------------- LDS-tiled fp32 GEMM: hbf = dis ⊙ (s0 @ W), bf16 output ----------------
__global__ __launch_bounds__(256) void k_gemm64(const float* __restrict__ s0,
                                                const float* __restrict__ W,
                                                const int* __restrict__ cnt1,
                                                uint2* __restrict__ Cbf) {
    __shared__ float At[64 * AT_STRIDE];
    __shared__ float Wl[64 * 64];
    const int t = threadIdx.x;
    const int l = t & 63, w = t >> 6;
    const int r0 = blockIdx.x * 64;
    const int rbase = w * 16 + (l >> 4) * 4;
    const int cbase = (l & 15) * 4;
    float acc[4][4] = {};

    {
        const float4* Wg = (const float4*)W;
        #pragma unroll
        for (int i = 0; i < 4; ++i) *(float4*)&Wl[(i * 256 + t) * 4] = Wg[i * 256 + t];
    }
    #pragma unroll
    for (int i = 0; i < 4; ++i) {
        int f   = i * 256 + t;
        int row = f >> 4;
        int kq  = f & 15;
        int gr  = r0 + row; if (gr > N_NODES - 1) gr = N_NODES - 1;
        float4 v = *(const float4*)(s0 + (size_t)gr * 64 + kq * 4);
        At[(kq * 4 + 0) * AT_STRIDE + row] = v.x;
        At[(kq * 4 + 1) * AT_STRIDE + row] = v.y;
        At[(kq * 4 + 2) * AT_STRIDE + row] = v.z;
        At[(kq * 4 + 3) * AT_STRIDE + row] = v.w;
    }
    __syncthreads();
    #pragma unroll 8
    for (int k = 0; k < 64; ++k) {
        float4 a4 = *(const float4*)&At[k * AT_STRIDE + rbase];
        float4 w4 = *(const float4*)&Wl[k * 64 + cbase];
        acc[0][0] += a4.x * w4.x; acc[0][1] += a4.x * w4.y; acc[0][2] += a4.x * w4.z; acc[0][3] += a4.x * w4.w;
        acc[1][0] += a4.y * w4.x; acc[1][1] += a4.y * w4.y; acc[1][2] += a4.y * w4.z; acc[1][3] += a4.y * w4.w;
        acc[2][0] += a4.z * w4.x; acc[2][1] += a4.z * w4.y; acc[2][2] += a4.z * w4.z; acc[2][3] += a4.z * w4.w;
        acc[3][0] += a4.w * w4.x; acc[3][1] += a4.w * w4.y; acc[3][2] += a4.w * w4.z; acc[3][3] += a4.w * w4.w;
    }
    #pragma unroll
    for (int r = 0; r < 4; ++r) {
        int gr = r0 + rbase + r;
        if (gr < N_NODES) {
            float d = rsqrtf(1.0f + (float)cnt1[gr]);
            float4 o = {d * acc[r][0], d * acc[r][1], d * acc[r][2], d * acc[r][3]};
            Cbf[(size_t)gr * 16 + (l & 15)] = pack_f4(o);
        }
    }
}

// ---------------- pool (batch sorted -> contiguous ranges) + head, 4 waves ----------------
__global__ __launch_bounds__(256) void k_pool_out(const float* __restrict__ xm,
                           const int* __restrict__ batch,
                           const float* __restrict__ Wout, const float* __restrict__ bout,
                           float* __restrict__ out) {
    __shared__ float red[4][64];
    __shared__ float sh[64];
    __shared__ float logits[OUT_DIM];
    int g = blockIdx.x;
    int t = threadIdx.x, f = t & 63, w = t >> 6;
    int lo = 0, hi = N_NODES;
    while (lo < hi) { int m = (lo + hi) >> 1; if (batch[m] < g) lo = m + 1; else hi = m; }
    int start = lo;
    hi = N_NODES;
    while (lo < hi) { int m = (lo + hi) >> 1; if (batch[m] < g + 1) lo = m + 1; else hi = m; }
    int end = lo;
    float a = 0.f;
    for (int i = start + w; i < end; i += 4)
        a += xm[(size_t)i * 64 + f];
    red[w][f] = a;
    __syncthreads();
    if (w == 0) {
        float cnt = (float)((end - start) > 0 ? (end - start) : 1);
        sh[f] = (red[0][f] + red[1][f] + red[2][f] + red[3][f]) / cnt;
    }
    __syncthreads();
    if (t < OUT_DIM) {
        float l = bout[t];
        for (int k = 0; k < 64; ++k) l += sh[k] * Wout[k * OUT_DIM + t];
        logits[t] = l;
    }
    __syncthreads();
    if (t < OUT_DIM) {
        float m = logits[0];
        for (int k = 1; k < OUT_DIM; ++k) m = fmaxf(m, logits[k]);
        float ssum = 0.f;
        for (int k = 0; k < OUT_DIM; ++k) ssum += expf(logits[k] - m);
        out[(size_t)g * OUT_DIM + t] = expf(logits[t] - m) / ssum;
    }
}

extern "C" void kernel_launch(void* const* d_in, const int* in_sizes, int n_in,
                              void* d_out, int out_size, void* d_ws, size_t ws_size,
                              hipStream_t stream) {
    const float* X     = (const float*)d_in[0];
    const int*   Lind  = (const int*)d_in[1];
    const int*   ind0  = Lind;
    const int*   ind1  = Lind + N_EDGES;
    const float* vals  = (const float*)d_in[2];
    const int*   batch = (const int*)d_in[3];
    const float* W1    = (const float*)d_in[4];
    const float* b1    = (const float*)d_in[5];
    const float* W2    = (const float*)d_in[6];
    const float* b2    = (const float*)d_in[7];
    const float* W3    = (const float*)d_in[8];
    const float* b3    = (const float*)d_in[9];
    const float* Wout  = (const float*)d_in[10];
    const float* bout  = (const float*)d_in[11];
    float* out = (float*)d_out;

    // workspace layout (4B words; fp32 buffers at %4==0 word offsets, bf16 at %2==0)
    int* cnt0    = (int*)d_ws;                     // 50000
    int* cnt1    = cnt0 + 50000;                   // 50000
    int2* c0pack = (int2*)(cnt1 + 50000);          // 2,400,000 int2
    int*  c1src  = (int*)(c0pack + 50000 * CAP);   // 2,400,000
    float* G0    = (float*)(c1src + 50000 * CAP);  // 3,200,000 (offset 7,300,000 %4==0)
    float* G1    = G0 + 3200000;                   // 3,200,000
    uint2* G2bf  = (uint2*)(G1 + 3200000);         // 800,000 uint2 (offset 13,700,000 words)
    uint2* Rbf   = G2bf + 800000;
    uint2* hbf   = Rbf + 800000;
    float* xm    = (float*)(hbf + 800000);         // 3,200,000 (offset 18,500,000 %4==0)
    // fp32 buffer reuse after producers die:
    float* x1    = G0;   // G0 dead after spmm1
    float* x2    = G1;   // G1 dead after spmm0

    const int B = 256;
    const int gatherGrid = 12500 * 64 / B;                // 3125 blocks (4 nodes/wave)
    const int tileGrid = GEMM_BLOCKS;                     // 782
    const int partGrid = NCHUNKS * 8;                     // 3128 (R14 config)

    // direct CSR build (no hist / no scan)
    k_zero_int<<<(100000 + B - 1) / B, B, 0, stream>>>(cnt0, 100000);  // cnt0+cnt1 contiguous
    k_scatter_direct<<<partGrid, B, 0, stream>>>(ind0, ind1, vals, cnt0, cnt1, c0pack, c1src);

    // layer-1 GEMMs: G0/G1 fp32, G2 bf16
    k_gemm1x3<<<tileGrid, B, 0, stream>>>(X, W1, G0, G1, G2bf);

    // Chebyshev via linearity (64-dim spmms, bf16 gathers):
    // R = G1 + 2*(L@G2);  h1' = dis*(L@R + G0 - G2)
    k_spmm64v<0><<<gatherGrid, B, 0, stream>>>(cnt0, c0pack, G2bf,
                                               (const float4*)G1, nullptr, cnt1, Rbf);
    k_spmm64v<1><<<gatherGrid, B, 0, stream>>>(cnt0, c0pack, Rbf,
                                               (const float4*)G0, G2bf, cnt1, hbf);

    // layer 1 conv (writes x1 fp32 into G0's space — G0 dead after spmm1)
    k_conv_gatherv<0><<<gatherGrid, B, 0, stream>>>(cnt1, c1src, hbf, b1,
                                                    nullptr, nullptr, (float4*)x1);

    // layer 2: hbf = dis*(x1@W2) in bf16, conv (x2 into G1's space)
    k_gemm64<<<tileGrid, B, 0, stream>>>(x1, W2, cnt1, hbf);
    k_conv_gatherv<0><<<gatherGrid, B, 0, stream>>>(cnt1, c1src, hbf, b2,
                                                    nullptr, nullptr, (float4*)x2);

    // layer 3: conv writes xm = (x1+x2+x3)/3 directly
    k_gemm64<<<tileGrid, B, 0, stream>>>(x2, W3, cnt1, hbf);
    k_conv_gatherv<1><<<gatherGrid, B, 0, stream>>>(cnt1, c1src, hbf, b3,
                                                    (const float4*)x1, (const float4*)x2, (float4*)xm);

    // pool + head
    k_pool_out<<<N_GRAPHS, B, 0, stream>>>(xm, batch, Wout, bout, out);
}

// Round 17
// 295.344 us; speedup vs baseline: 1.2325x; 1.0008x over previous
//
#include <hip/hip_runtime.h>
#include <hip/hip_bf16.h>
#include <hip/hip_fp16.h>

#define N_NODES 50000
#define N_EDGES 800000
#define IN_DIM 128
#define F_SIZE 64
#define N_GRAPHS 512
#define OUT_DIM 10
#define EDGE_CHUNK 2048
#define NCHUNKS ((N_EDGES + EDGE_CHUNK - 1) / EDGE_CHUNK)   // 391
#define NODES_PER_XCD ((N_NODES + 7) / 8)                    // 6250
#define GEMM_BLOCKS 782        // ceil(50000/64)
#define CAP 48                 // per-node CSR bucket capacity (max degree ~45 @ Poisson(16))

// ---------------- bf16 pack/unpack helpers (round-to-nearest-even) ----------------
__device__ __forceinline__ unsigned int pack_bf2(float a, float b) {
    unsigned int ua = __float_as_uint(a);
    unsigned int ub = __float_as_uint(b);
    ua += 0x7fffu + ((ua >> 16) & 1u);
    ub += 0x7fffu + ((ub >> 16) & 1u);
    return (ua >> 16) | (ub & 0xffff0000u);
}
__device__ __forceinline__ uint2 pack_f4(float4 o) {
    return make_uint2(pack_bf2(o.x, o.y), pack_bf2(o.z, o.w));
}
__device__ __forceinline__ float4 unpack_f4(uint2 u) {
    float4 f;
    f.x = __uint_as_float(u.x << 16);
    f.y = __uint_as_float(u.x & 0xffff0000u);
    f.z = __uint_as_float(u.y << 16);
    f.w = __uint_as_float(u.y & 0xffff0000u);
    return f;
}

// ---------------- utility ----------------
__global__ void k_zero_int(int* __restrict__ p, int n) {
    int i = blockIdx.x * blockDim.x + threadIdx.x;
    if (i < n) p[i] = 0;
}

// ---------------- XCD-partitioned direct scatter ----------------
// c0 payload: one u32 = (col << 16) | fp16(val).  c1 payload: src node id (u32).
__global__ __launch_bounds__(256) void k_scatter_direct(const int* __restrict__ ind0,
                                                        const int* __restrict__ ind1,
                                                        const float* __restrict__ vals,
                                                        int* __restrict__ cnt0, int* __restrict__ cnt1,
                                                        unsigned int* __restrict__ c0pack,
                                                        int* __restrict__ c1src) {
    int xcd = blockIdx.x & 7;
    int chunk = blockIdx.x >> 3;
    int lo = xcd * NODES_PER_XCD, hi = lo + NODES_PER_XCD;
    int base = chunk * EDGE_CHUNK;
    int end = base + EDGE_CHUNK; if (end > N_EDGES) end = N_EDGES;
    for (int e = base + threadIdx.x; e < end; e += 256) {
        int r = ind0[e];
        int c = ind1[e];
        if (r >= lo && r < hi) {
            int p0 = atomicAdd(&cnt0[r], 1);
            unsigned int hv = (unsigned int)__half_as_ushort(__float2half(vals[e]));
            c0pack[r * CAP + p0] = ((unsigned int)c << 16) | hv;
        }
        if (c >= lo && c < hi) {
            int p1 = atomicAdd(&cnt1[c], 1);
            c1src[c * CAP + p1] = r;
        }
    }
}

// ---------------- layer-1 triple GEMM: all outputs bf16 ----------------
#define AT_STRIDE 68
__global__ __launch_bounds__(256) void k_gemm1x3(const float* __restrict__ X,
                                                 const float* __restrict__ W1,
                                                 uint2* __restrict__ G0bf,
                                                 uint2* __restrict__ G1bf,
                                                 uint2* __restrict__ G2bf) {
    __shared__ float At[64 * AT_STRIDE];
    __shared__ float Wl[64 * 64];
    const int t = threadIdx.x;
    const int l = t & 63, w = t >> 6;
    const int r0 = blockIdx.x * 64;
    const int rbase = w * 16 + (l >> 4) * 4;
    const int cbase = (l & 15) * 4;
    float acc[3][4][4] = {};

    #pragma unroll
    for (int ch = 0; ch < 2; ++ch) {
        const int koff = ch * 64;
        #pragma unroll
        for (int i = 0; i < 4; ++i) {
            int f   = i * 256 + t;
            int row = f >> 4;
            int kq  = f & 15;
            int gr  = r0 + row; if (gr > N_NODES - 1) gr = N_NODES - 1;
            float4 v = *(const float4*)(X + (size_t)gr * IN_DIM + koff + kq * 4);
            At[(kq * 4 + 0) * AT_STRIDE + row] = v.x;
            At[(kq * 4 + 1) * AT_STRIDE + row] = v.y;
            At[(kq * 4 + 2) * AT_STRIDE + row] = v.z;
            At[(kq * 4 + 3) * AT_STRIDE + row] = v.w;
        }
        #pragma unroll
        for (int sg = 0; sg < 3; ++sg) {
            const float4* Wg = (const float4*)(W1 + ((size_t)sg * 128 + koff) * 64);
            float4 wtmp[4];
            #pragma unroll
            for (int i = 0; i < 4; ++i) wtmp[i] = Wg[i * 256 + t];
            __syncthreads();
            #pragma unroll
            for (int i = 0; i < 4; ++i) *(float4*)&Wl[(i * 256 + t) * 4] = wtmp[i];
            __syncthreads();
            #pragma unroll 8
            for (int k = 0; k < 64; ++k) {
                float4 a4 = *(const float4*)&At[k * AT_STRIDE + rbase];
                float4 w4 = *(const float4*)&Wl[k * 64 + cbase];
                acc[sg][0][0] += a4.x * w4.x; acc[sg][0][1] += a4.x * w4.y; acc[sg][0][2] += a4.x * w4.z; acc[sg][0][3] += a4.x * w4.w;
                acc[sg][1][0] += a4.y * w4.x; acc[sg][1][1] += a4.y * w4.y; acc[sg][1][2] += a4.y * w4.z; acc[sg][1][3] += a4.y * w4.w;
                acc[sg][2][0] += a4.z * w4.x; acc[sg][2][1] += a4.z * w4.y; acc[sg][2][2] += a4.z * w4.z; acc[sg][2][3] += a4.z * w4.w;
                acc[sg][3][0] += a4.w * w4.x; acc[sg][3][1] += a4.w * w4.y; acc[sg][3][2] += a4.w * w4.z; acc[sg][3][3] += a4.w * w4.w;
            }
        }
        __syncthreads();
    }
    uint2* Gs[3] = {G0bf, G1bf, G2bf};
    #pragma unroll
    for (int sg = 0; sg < 3; ++sg) {
        #pragma unroll
        for (int r = 0; r < 4; ++r) {
            int gr = r0 + rbase + r;
            if (gr < N_NODES) {
                float4 o = {acc[sg][r][0], acc[sg][r][1], acc[sg][r][2], acc[sg][r][3]};
                Gs[sg][(size_t)gr * 16 + (l & 15)] = pack_f4(o);
            }
        }
    }
}

// ---------------- bf16-gather SpMM: wave = 4 nodes, 16 lanes/row ----------------
// MODE 0: Rbf = A(G1bf) + 2*acc(src=G2bf)
// MODE 1: hbf = dis*(acc(src=Rbf) + A(G0bf) - B(G2bf))
template<int MODE>
__global__ __launch_bounds__(256) void k_spmm64v(const int* __restrict__ cnt0,
                          const unsigned int* __restrict__ pack,
                          const uint2* __restrict__ srcbf, const uint2* __restrict__ Abf,
                          const uint2* __restrict__ Bbf, const int* __restrict__ cnt1,
                          uint2* __restrict__ dstbf) {
    int t = blockIdx.x * blockDim.x + threadIdx.x;
    int wid = t >> 6, lane = t & 63;
    int grp = lane >> 4, sub = lane & 15;
    int node = wid * 4 + grp;
    if (node >= N_NODES) return;
    int s = node * CAP;
    int e = s + cnt0[node];
    float4 acc = {0.f, 0.f, 0.f, 0.f};
    int j = s;
    for (; j + 3 < e; j += 4) {
        unsigned int p0 = pack[j], p1 = pack[j + 1], p2 = pack[j + 2], p3 = pack[j + 3];
        float4 r0 = unpack_f4(srcbf[(size_t)(p0 >> 16) * 16 + sub]);
        float4 r1 = unpack_f4(srcbf[(size_t)(p1 >> 16) * 16 + sub]);
        float4 r2 = unpack_f4(srcbf[(size_t)(p2 >> 16) * 16 + sub]);
        float4 r3 = unpack_f4(srcbf[(size_t)(p3 >> 16) * 16 + sub]);
        float v0 = __half2float(__ushort_as_half((unsigned short)(p0 & 0xffffu)));
        float v1 = __half2float(__ushort_as_half((unsigned short)(p1 & 0xffffu)));
        float v2 = __half2float(__ushort_as_half((unsigned short)(p2 & 0xffffu)));
        float v3 = __half2float(__ushort_as_half((unsigned short)(p3 & 0xffffu)));
        acc.x += v0 * r0.x + v1 * r1.x + v2 * r2.x + v3 * r3.x;
        acc.y += v0 * r0.y + v1 * r1.y + v2 * r2.y + v3 * r3.y;
        acc.z += v0 * r0.z + v1 * r1.z + v2 * r2.z + v3 * r3.z;
        acc.w += v0 * r0.w + v1 * r1.w + v2 * r2.w + v3 * r3.w;
    }
    for (; j < e; ++j) {
        unsigned int p = pack[j];
        float4 r = unpack_f4(srcbf[(size_t)(p >> 16) * 16 + sub]);
        float v = __half2float(__ushort_as_half((unsigned short)(p & 0xffffu)));
        acc.x += v * r.x; acc.y += v * r.y; acc.z += v * r.z; acc.w += v * r.w;
    }
    size_t idx = (size_t)node * 16 + sub;
    float4 a = unpack_f4(Abf[idx]);
    float4 o;
    if (MODE == 0) {
        o.x = a.x + 2.f * acc.x; o.y = a.y + 2.f * acc.y;
        o.z = a.z + 2.f * acc.z; o.w = a.w + 2.f * acc.w;
    } else {
        float4 bb = unpack_f4(Bbf[idx]);
        float d = rsqrtf(1.0f + (float)cnt1[node]);
        o.x = d * (acc.x + a.x - bb.x); o.y = d * (acc.y + a.y - bb.y);
        o.z = d * (acc.z + a.z - bb.z); o.w = d * (acc.w + a.w - bb.w);
    }
    dstbf[idx] = pack_f4(o);
}

// ---------------- bf16-gather conv ----------------
// FINAL=0: xbf = bf16(relu(dis*(acc + self) + b))
// FINAL=1: xm  = (x1 + x2 + relu(...))/3   (fp32, feeds pool only)
template<int FINAL>
__global__ void k_conv_gatherv(const int* __restrict__ cnt1, const int* __restrict__ csrc,
                               const uint2* __restrict__ hbf,
                               const float* __restrict__ b,
                               const uint2* __restrict__ x1bf, const uint2* __restrict__ x2bf,
                               uint2* __restrict__ outbf, float4* __restrict__ outf) {
    int t = blockIdx.x * blockDim.x + threadIdx.x;
    int wid = t >> 6, lane = t & 63;
    int grp = lane >> 4, sub = lane & 15;
    int node = wid * 4 + grp;
    if (node >= N_NODES) return;
    int deg = cnt1[node];
    int s = node * CAP;
    int e = s + deg;
    float4 acc = {0.f, 0.f, 0.f, 0.f};
    int j = s;
    for (; j + 3 < e; j += 4) {
        int s0 = csrc[j], s1 = csrc[j + 1], s2 = csrc[j + 2], s3 = csrc[j + 3];
        float4 r0 = unpack_f4(hbf[(size_t)s0 * 16 + sub]);
        float4 r1 = unpack_f4(hbf[(size_t)s1 * 16 + sub]);
        float4 r2 = unpack_f4(hbf[(size_t)s2 * 16 + sub]);
        float4 r3 = unpack_f4(hbf[(size_t)s3 * 16 + sub]);
        acc.x += (r0.x + r1.x) + (r2.x + r3.x);
        acc.y += (r0.y + r1.y) + (r2.y + r3.y);
        acc.z += (r0.z + r1.z) + (r2.z + r3.z);
        acc.w += (r0.w + r1.w) + (r2.w + r3.w);
    }
    for (; j < e; ++j) {
        float4 r = unpack_f4(hbf[(size_t)csrc[j] * 16 + sub]);
        acc.x += r.x; acc.y += r.y; acc.z += r.z; acc.w += r.w;
    }
    size_t idx = (size_t)node * 16 + sub;
    float4 sl = unpack_f4(hbf[idx]);      // self loop
    float d = rsqrtf(1.0f + (float)deg);
    float4 bv = ((const float4*)b)[sub];
    float4 o;
    o.x = fmaxf(d * (acc.x + sl.x) + bv.x, 0.f);
    o.y = fmaxf(d * (acc.y + sl.y) + bv.y, 0.f);
    o.z = fmaxf(d * (acc.z + sl.z) + bv.z, 0.f);
    o.w = fmaxf(d * (acc.w + sl.w) + bv.w, 0.f);
    if (FINAL) {
        float4 a1 = unpack_f4(x1bf[idx]), a2 = unpack_f4(x2bf[idx]);
        const float third = 1.f / 3.f;
        o.x = (a1.x + a2.x + o.x) * third;
        o.y = (a1.y + a2.y + o.y) * third;
        o.z = (a1.z + a2.z + o.z) * third;
        o.w = (a1.w + a2.w + o.w) * third;
        outf[idx] = o;
    } else {
        outbf[idx] = pack_f4(o);
    }
}

// ---------------- LDS-tiled GEMM: hbf = dis ⊙ (s0bf @ W), bf16 in/out ----------------
__global__ __launch_bounds__(256) void k_gemm64(const uint2* __restrict__ s0bf,
                                                const float* __restrict__ W,
                                                const int* __restrict__ cnt1,
                                                uint2* __restrict__ Cbf) {
    __shared__ float At[64 * AT_STRIDE];
    __shared__ float Wl[64 * 64];
    const int t = threadIdx.x;
    const int l = t & 63, w = t >> 6;
    const int r0 = blockIdx.x * 64;
    const int rbase = w * 16 + (l >> 4) * 4;
    const int cbase = (l & 15) * 4;
    float acc[4][4] = {};

    {
        const float4* Wg = (const float4*)W;
        #pragma unroll
        for (int i = 0; i < 4; ++i) *(float4*)&Wl[(i * 256 + t) * 4] = Wg[i * 256 + t];
    }
    #pragma unroll
    for (int i = 0; i < 4; ++i) {
        int f   = i * 256 + t;
        int row = f >> 4;
        int kq  = f & 15;
        int gr  = r0 + row; if (gr > N_NODES - 1) gr = N_NODES - 1;
        float4 v = unpack_f4(s0bf[(size_t)gr * 16 + kq]);
        At[(kq * 4 + 0) * AT_STRIDE + row] = v.x;
        At[(kq * 4 + 1) * AT_STRIDE + row] = v.y;
        At[(kq * 4 + 2) * AT_STRIDE + row] = v.z;
        At[(kq * 4 + 3) * AT_STRIDE + row] = v.w;
    }
    __syncthreads();
    #pragma unroll 8
    for (int k = 0; k < 64; ++k) {
        float4 a4 = *(const float4*)&At[k * AT_STRIDE + rbase];
        float4 w4 = *(const float4*)&Wl[k * 64 + cbase];
        acc[0][0] += a4.x * w4.x; acc[0][1] += a4.x * w4.y; acc[0][2] += a4.x * w4.z; acc[0][3] += a4.x * w4.w;
        acc[1][0] += a4.y * w4.x; acc[1][1] += a4.y * w4.y; acc[1][2] += a4.y * w4.z; acc[1][3] += a4.y * w4.w;
        acc[2][0] += a4.z * w4.x; acc[2][1] += a4.z * w4.y; acc[2][2] += a4.z * w4.z; acc[2][3] += a4.z * w4.w;
        acc[3][0] += a4.w * w4.x; acc[3][1] += a4.w * w4.y; acc[3][2] += a4.w * w4.z; acc[3][3] += a4.w * w4.w;
    }
    #pragma unroll
    for (int r = 0; r < 4; ++r) {
        int gr = r0 + rbase + r;
        if (gr < N_NODES) {
            float d = rsqrtf(1.0f + (float)cnt1[gr]);
            float4 o = {d * acc[r][0], d * acc[r][1], d * acc[r][2], d * acc[r][3]};
            Cbf[(size_t)gr * 16 + (l & 15)] = pack_f4(o);
        }
    }
}

// ---------------- pool (batch sorted -> contiguous ranges) + head, 4 waves ----------------
__global__ __launch_bounds__(256) void k_pool_out(const float* __restrict__ xm,
                           const int* __restrict__ batch,
                           const float* __restrict__ Wout, const float* __restrict__ bout,
                           float* __restrict__ out) {
    __shared__ float red[4][64];
    __shared__ float sh[64];
    __shared__ float logits[OUT_DIM];
    int g = blockIdx.x;
    int t = threadIdx.x, f = t & 63, w = t >> 6;
    int lo = 0, hi = N_NODES;
    while (lo < hi) { int m = (lo + hi) >> 1; if (batch[m] < g) lo = m + 1; else hi = m; }
    int start = lo;
    hi = N_NODES;
    while (lo < hi) { int m = (lo + hi) >> 1; if (batch[m] < g + 1) lo = m + 1; else hi = m; }
    int end = lo;
    float a = 0.f;
    for (int i = start + w; i < end; i += 4)
        a += xm[(size_t)i * 64 + f];
    red[w][f] = a;
    __syncthreads();
    if (w == 0) {
        float cnt = (float)((end - start) > 0 ? (end - start) : 1);
        sh[f] = (red[0][f] + red[1][f] + red[2][f] + red[3][f]) / cnt;
    }
    __syncthreads();
    if (t < OUT_DIM) {
        float l = bout[t];
        for (int k = 0; k < 64; ++k) l += sh[k] * Wout[k * OUT_DIM + t];
        logits[t] = l;
    }
    __syncthreads();
    if (t < OUT_DIM) {
        float m = logits[0];
        for (int k = 1; k < OUT_DIM; ++k) m = fmaxf(m, logits[k]);
        float ssum = 0.f;
        for (int k = 0; k < OUT_DIM; ++k) ssum += expf(logits[k] - m);
        out[(size_t)g * OUT_DIM + t] = expf(logits[t] - m) / ssum;
    }
}

extern "C" void kernel_launch(void* const* d_in, const int* in_sizes, int n_in,
                              void* d_out, int out_size, void* d_ws, size_t ws_size,
                              hipStream_t stream) {
    const float* X     = (const float*)d_in[0];
    const int*   Lind  = (const int*)d_in[1];
    const int*   ind0  = Lind;
    const int*   ind1  = Lind + N_EDGES;
    const float* vals  = (const float*)d_in[2];
    const int*   batch = (const int*)d_in[3];
    const float* W1    = (const float*)d_in[4];
    const float* b1    = (const float*)d_in[5];
    const float* W2    = (const float*)d_in[6];
    const float* b2    = (const float*)d_in[7];
    const float* W3    = (const float*)d_in[8];
    const float* b3    = (const float*)d_in[9];
    const float* Wout  = (const float*)d_in[10];
    const float* bout  = (const float*)d_in[11];
    float* out = (float*)d_out;

    // workspace layout (4B words)
    int* cnt0    = (int*)d_ws;                     // 50000
    int* cnt1    = cnt0 + 50000;                   // 50000
    unsigned int* c0pack = (unsigned int*)(cnt1 + 50000);  // 2,400,000 u32
    int*  c1src  = (int*)(c0pack + 50000 * CAP);   // 2,400,000
    uint2* G0bf  = (uint2*)(c1src + 50000 * CAP);  // 800,000 uint2 (word off 4,900,000, even)
    uint2* G1bf  = G0bf + 800000;
    uint2* G2bf  = G1bf + 800000;
    uint2* Rbf   = G2bf + 800000;
    uint2* hbf   = Rbf + 800000;
    float* xm    = (float*)(hbf + 800000);         // 3,200,000 fp32 (word off 12,900,000 %4==0)
    // bf16 buffer reuse after producers die:
    uint2* x1bf  = G0bf;   // G0 dead after spmm1
    uint2* x2bf  = G1bf;   // G1 dead after spmm0

    const int B = 256;
    const int gatherGrid = 12500 * 64 / B;                // 3125 blocks (4 nodes/wave)
    const int tileGrid = GEMM_BLOCKS;                     // 782
    const int partGrid = NCHUNKS * 8;                     // 3128

    // direct CSR build (no hist / no scan)
    k_zero_int<<<(100000 + B - 1) / B, B, 0, stream>>>(cnt0, 100000);  // cnt0+cnt1 contiguous
    k_scatter_direct<<<partGrid, B, 0, stream>>>(ind0, ind1, vals, cnt0, cnt1, c0pack, c1src);

    // layer-1 GEMMs: G0/G1/G2 bf16
    k_gemm1x3<<<tileGrid, B, 0, stream>>>(X, W1, G0bf, G1bf, G2bf);

    // Chebyshev via linearity (64-dim spmms, bf16 gathers):
    // R = G1 + 2*(L@G2);  h1' = dis*(L@R + G0 - G2)
    k_spmm64v<0><<<gatherGrid, B, 0, stream>>>(cnt0, c0pack, G2bf, G1bf, nullptr, cnt1, Rbf);
    k_spmm64v<1><<<gatherGrid, B, 0, stream>>>(cnt0, c0pack, Rbf, G0bf, G2bf, cnt1, hbf);

    // layer 1 conv (writes x1bf into G0bf's space)
    k_conv_gatherv<0><<<gatherGrid, B, 0, stream>>>(cnt1, c1src, hbf, b1,
                                                    nullptr, nullptr, x1bf, nullptr);

    // layer 2: hbf = dis*(x1@W2), conv (x2bf into G1bf's space)
    k_gemm64<<<tileGrid, B, 0, stream>>>(x1bf, W2, cnt1, hbf);
    k_conv_gatherv<0><<<gatherGrid, B, 0, stream>>>(cnt1, c1src, hbf, b2,
                                                    nullptr, nullptr, x2bf, nullptr);

    // layer 3: conv writes xm = (x1+x2+x3)/3 (fp32)
    k_gemm64<<<tileGrid, B, 0, stream>>>(x2bf, W3, cnt1, hbf);
    k_conv_gatherv<1><<<gatherGrid, B, 0, stream>>>(cnt1, c1src, hbf, b3,
                                                    x1bf, x2bf, nullptr, (float4*)xm);

    // pool + head
    k_pool_out<<<N_GRAPHS, B, 0, stream>>>(xm, batch, Wout, bout, out);
}